// Round 9
// baseline (3884.798 us; speedup 1.0000x reference)
//
#include <hip/hip_runtime.h>

#define D 512
#define C 1024
#define BMF 64       // rows per block
#define KSTEPS 16    // D / 32
#define NCC 8        // C / 128

typedef _Float16 f16x8 __attribute__((ext_vector_type(8)));
typedef float f32x4 __attribute__((ext_vector_type(4)));

// lexicographic (score, index) insert into sorted top-3
__device__ __forceinline__ void ins3(float s, int i,
                                     float& s1, int& i1, float& s2, int& i2,
                                     float& s3, int& i3) {
    if (s < s1 || (s == s1 && i < i1)) { s3 = s2; i3 = i2; s2 = s1; i2 = i1; s1 = s; i1 = i; }
    else if (s < s2 || (s == s2 && i < i2)) { s3 = s2; i3 = i2; s2 = s; i2 = i; }
    else if (s < s3 || (s == s3 && i < i3)) { s3 = s; i3 = i; }
}

// ---- ||c||^2 for all Q*C codes (fp32)
__global__ __launch_bounds__(256) void cbnorm_kernel(const float* __restrict__ cb,
                                                     float* __restrict__ cbn) {
    int code = blockIdx.x * 4 + (threadIdx.x >> 6);
    int lane = threadIdx.x & 63;
    const float* row = cb + (size_t)code * D;
    float4 a = *(const float4*)(row + lane * 8);
    float4 b = *(const float4*)(row + lane * 8 + 4);
    float s = a.x*a.x + a.y*a.y + a.z*a.z + a.w*a.w
            + b.x*b.x + b.y*b.y + b.z*b.z + b.w*b.w;
    #pragma unroll
    for (int off = 32; off > 0; off >>= 1) s += __shfl_down(s, off, 64);
    if (lane == 0) cbn[code] = s;
}

// ---- f16 plane of codebooks in MFMA-fragment tile order.
// uint4 index t = ((q*8+cc)*16+ks)*512 + tile*64 + ksub*16 + col
__global__ __launch_bounds__(256) void cb_split_kernel(const float* __restrict__ cbs,
                                                       uint4* __restrict__ hi_plane) {
    int t = blockIdx.x * 256 + threadIdx.x;
    int rg = t >> 9;
    int u  = t & 511;
    int q  = rg >> 7;
    int cc = (rg >> 4) & 7;
    int ks = rg & 15;
    int tile = u >> 6;
    int ksub = (u >> 4) & 3;
    int col  = u & 15;
    int code = cc * 128 + tile * 16 + col;
    int d0   = ks * 32 + ksub * 8;
    const float* src = cbs + ((size_t)q * C + code) * D + d0;
    float4 v0 = *(const float4*)src;
    float4 v1 = *(const float4*)(src + 4);
    float xv[8] = {v0.x, v0.y, v0.z, v0.w, v1.x, v1.y, v1.z, v1.w};
    f16x8 h;
    #pragma unroll
    for (int e = 0; e < 8; ++e) h[e] = (_Float16)xv[e];
    hi_plane[t] = __builtin_bit_cast(uint4, h);
}

// ---- fused VQ step: A in LDS, B streamed from L2 (no hot-loop barriers),
//      running top-3, sequential fp64 rescore, residual update, loss.
__global__ __launch_bounds__(512, 2) void vq_fused_step(
    const float* __restrict__ rin,
    float*       __restrict__ rout,
    const uint4* __restrict__ bplane,  // [128 its][512] uint4, fragment order (1 MB)
    const float* __restrict__ cbq,     // fp32 codebook [C][D]
    const float* __restrict__ cbnq,    // [C]
    float* __restrict__ idx_out,
    float* __restrict__ blockloss,     // [nblk] for this q
    int q, int nq)
{
    __shared__ uint4  A_lds[4096];     // 64 KiB: 16 ks x (4 tiles x 64)
    __shared__ float4 rowtop[BMF][4];  // per-row top-3 per wn column slice (4 KiB)
    __shared__ float  wls[8];

    const int tid  = threadIdx.x;
    const int lane = tid & 63;
    const int w    = tid >> 6;         // 0..7
    const int wm   = w >> 2;           // 0..1  (32-row half)
    const int wn   = w & 3;            // 0..3  (32-code quarter per chunk)
    const int bp   = blockIdx.x * BMF;

    // ---- stage A: fp32 -> f16 fragments (one time). lane covers d = lane*8..+8
    {
        const int ks = lane >> 2, ksub = lane & 3;
        #pragma unroll
        for (int j = 0; j < 8; ++j) {
            int row = w * 8 + j;
            const float* src = rin + (size_t)(bp + row) * D + lane * 8;
            float4 v0 = *(const float4*)src;
            float4 v1 = *(const float4*)(src + 4);
            float xv[8] = {v0.x, v0.y, v0.z, v0.w, v1.x, v1.y, v1.z, v1.w};
            f16x8 h;
            #pragma unroll
            for (int e = 0; e < 8; ++e) h[e] = (_Float16)xv[e];
            int idx = ks * 256 + (row >> 4) * 64 + ksub * 16 + (row & 15);
            A_lds[idx ^ (ks & 7)] = __builtin_bit_cast(uint4, h);  // bank swizzle
        }
    }
    __syncthreads();   // A ready; no more barriers until after the K-loop

    float S1[2][4], S2[2][4], S3[2][4];
    int   I1[2][4], I2[2][4], I3[2][4];
    #pragma unroll
    for (int mt = 0; mt < 2; ++mt)
        #pragma unroll
        for (int r = 0; r < 4; ++r) {
            S1[mt][r] = S2[mt][r] = S3[mt][r] = 3.4e38f;
            I1[mt][r] = I2[mt][r] = I3[mt][r] = 1023;
        }

    f32x4 acc[2][2];
    #pragma unroll
    for (int mt = 0; mt < 2; ++mt)
        #pragma unroll
        for (int nt = 0; nt < 2; ++nt) acc[mt][nt] = (f32x4){0.f, 0.f, 0.f, 0.f};

    const int t0 = (wn * 2 + 0) * 64 + lane;
    const int t1 = (wn * 2 + 1) * 64 + lane;
    uint4 b0 = bplane[t0];
    uint4 b1 = bplane[t1];

    for (int it = 0; it < 128; ++it) {
        int nxt = (it + 1 < 128) ? (it + 1) : 127;
        uint4 n0 = bplane[(size_t)nxt * 512 + t0];
        uint4 n1 = bplane[(size_t)nxt * 512 + t1];
        int ks = it & 15;
        f16x8 bf0 = __builtin_bit_cast(f16x8, b0);
        f16x8 bf1 = __builtin_bit_cast(f16x8, b1);
        #pragma unroll
        for (int mt = 0; mt < 2; ++mt) {
            int aidx = (ks * 256 + (wm * 2 + mt) * 64 + lane) ^ (ks & 7);
            f16x8 af = __builtin_bit_cast(f16x8, A_lds[aidx]);
            acc[mt][0] = __builtin_amdgcn_mfma_f32_16x16x32_f16(af, bf0, acc[mt][0], 0, 0, 0);
            acc[mt][1] = __builtin_amdgcn_mfma_f32_16x16x32_f16(af, bf1, acc[mt][1], 0, 0, 0);
        }
        if (ks == 15) {     // end of a 128-code chunk: fold scores, reset acc
            int cc = it >> 4;
            #pragma unroll
            for (int nt = 0; nt < 2; ++nt) {
                int code = cc * 128 + (wn * 2 + nt) * 16 + (lane & 15);
                float nrm = cbnq[code];
                #pragma unroll
                for (int mt = 0; mt < 2; ++mt)
                    #pragma unroll
                    for (int r = 0; r < 4; ++r) {
                        float s = fmaf(-2.f, acc[mt][nt][r], nrm);
                        ins3(s, code, S1[mt][r], I1[mt][r], S2[mt][r], I2[mt][r],
                             S3[mt][r], I3[mt][r]);
                    }
            }
            #pragma unroll
            for (int mt = 0; mt < 2; ++mt)
                #pragma unroll
                for (int nt = 0; nt < 2; ++nt) acc[mt][nt] = (f32x4){0.f, 0.f, 0.f, 0.f};
        }
        b0 = n0; b1 = n1;
    }

    // merge top-3 across the 16 lanes of each row-group
    #pragma unroll
    for (int mt = 0; mt < 2; ++mt)
        #pragma unroll
        for (int r = 0; r < 4; ++r) {
            #pragma unroll
            for (int m = 1; m < 16; m <<= 1) {
                float o1 = __shfl_xor(S1[mt][r], m, 64); int oi1 = __shfl_xor(I1[mt][r], m, 64);
                float o2 = __shfl_xor(S2[mt][r], m, 64); int oi2 = __shfl_xor(I2[mt][r], m, 64);
                float o3 = __shfl_xor(S3[mt][r], m, 64); int oi3 = __shfl_xor(I3[mt][r], m, 64);
                ins3(o1, oi1, S1[mt][r], I1[mt][r], S2[mt][r], I2[mt][r], S3[mt][r], I3[mt][r]);
                ins3(o2, oi2, S1[mt][r], I1[mt][r], S2[mt][r], I2[mt][r], S3[mt][r], I3[mt][r]);
                ins3(o3, oi3, S1[mt][r], I1[mt][r], S2[mt][r], I2[mt][r], S3[mt][r], I3[mt][r]);
            }
        }
    if ((lane & 15) == 0) {
        int hi = lane >> 4;
        #pragma unroll
        for (int mt = 0; mt < 2; ++mt)
            #pragma unroll
            for (int r = 0; r < 4; ++r) {
                int rr = wm * 32 + mt * 16 + hi * 4 + r;
                unsigned pk = (unsigned)I1[mt][r] | ((unsigned)I2[mt][r] << 10)
                            | ((unsigned)I3[mt][r] << 20);
                rowtop[rr][wn] = make_float4(S1[mt][r], S2[mt][r], S3[mt][r],
                                             __builtin_bit_cast(float, pk));
            }
    }
    __syncthreads();

    // ---- per-row: merge 4 slices, SEQUENTIAL fp64 rescore (register-light),
    //      reload winner, update residual, loss
    float wsum = 0.f;
    for (int j = 0; j < 8; ++j) {
        int rr = w * 8 + j;
        float s1 = 3.4e38f, s2 = 3.4e38f, s3 = 3.4e38f;
        int i1 = 1023, i2 = 1023, i3 = 1023;
        #pragma unroll
        for (int sl = 0; sl < 4; ++sl) {
            float4 t = rowtop[rr][sl];
            unsigned pk = __builtin_bit_cast(unsigned, t.w);
            ins3(t.x, (int)(pk & 1023),         s1, i1, s2, i2, s3, i3);
            ins3(t.y, (int)((pk >> 10) & 1023), s1, i1, s2, i2, s3, i3);
            ins3(t.z, (int)((pk >> 20) & 1023), s1, i1, s2, i2, s3, i3);
        }
        size_t grow = (size_t)(bp + rr);
        const float* rrow = rin + grow * D;
        float4 r0 = *(const float4*)(rrow + lane * 8);
        float4 r1 = *(const float4*)(rrow + lane * 8 + 4);
        float ra[8] = {r0.x, r0.y, r0.z, r0.w, r1.x, r1.y, r1.z, r1.w};

        double bd = 1.0e300;
        int fi = 1023;
        int cand[3] = {i1, i2, i3};
        #pragma unroll
        for (int k = 0; k < 3; ++k) {
            const float* c = cbq + (size_t)cand[k] * D;
            float4 c0 = *(const float4*)(c + lane * 8);
            float4 c1 = *(const float4*)(c + lane * 8 + 4);
            float cv[8] = {c0.x, c0.y, c0.z, c0.w, c1.x, c1.y, c1.z, c1.w};
            double dk = 0.0;
            #pragma unroll
            for (int e = 0; e < 8; ++e) {
                double cd = (double)cv[e];
                dk += cd * cd - 2.0 * (double)ra[e] * cd;
            }
            #pragma unroll
            for (int m = 32; m > 0; m >>= 1) dk += __shfl_xor(dk, m, 64);
            if (dk < bd || (dk == bd && cand[k] < fi)) { bd = dk; fi = cand[k]; }
        }
        if (lane == 0) idx_out[grow * nq + q] = (float)fi;

        const float* cw = cbq + (size_t)fi * D;
        float4 w0v = *(const float4*)(cw + lane * 8);
        float4 w1v = *(const float4*)(cw + lane * 8 + 4);
        float cwv[8] = {w0v.x, w0v.y, w0v.z, w0v.w, w1v.x, w1v.y, w1v.z, w1v.w};
        float nv[8];
        #pragma unroll
        for (int e = 0; e < 8; ++e) {
            nv[e] = ra[e] - cwv[e];
            wsum = fmaf(nv[e], nv[e], wsum);
        }
        float4 o0 = {nv[0], nv[1], nv[2], nv[3]};
        float4 o1 = {nv[4], nv[5], nv[6], nv[7]};
        *(float4*)(rout + grow * D + lane * 8)     = o0;
        *(float4*)(rout + grow * D + lane * 8 + 4) = o1;
    }
    #pragma unroll
    for (int off = 32; off > 0; off >>= 1) wsum += __shfl_down(wsum, off, 64);
    if (lane == 0) wls[w] = wsum;
    __syncthreads();
    if (tid == 0) {
        float s = 0.f;
        #pragma unroll
        for (int k = 0; k < 8; ++k) s += wls[k];
        blockloss[blockIdx.x] = s;
    }
}

// ---- quantized = x - final_residual (in place); blocks 0..nq-1 reduce losses.
__global__ __launch_bounds__(256) void finalize_kernel(
    const float* __restrict__ x, float* __restrict__ outq,
    const float* __restrict__ blockloss,
    float* __restrict__ losses, float invPD, int n4, int nq, int nblk)
{
    if (blockIdx.x < (unsigned)nq) {
        __shared__ float wls[4];
        int q = blockIdx.x;
        float s = 0.f;
        for (int i = threadIdx.x; i < nblk; i += 256)
            s += blockloss[(size_t)q * nblk + i];
        #pragma unroll
        for (int off = 32; off > 0; off >>= 1) s += __shfl_down(s, off, 64);
        if ((threadIdx.x & 63) == 0) wls[threadIdx.x >> 6] = s;
        __syncthreads();
        if (threadIdx.x == 0) {
            float vq = (wls[0] + wls[1] + wls[2] + wls[3]) * invPD;
            losses[q] = vq;
            losses[nq + q] = 0.25f * vq;
        }
    }
    int stride = gridDim.x * blockDim.x;
    for (int i = blockIdx.x * blockDim.x + threadIdx.x; i < n4; i += stride) {
        float4 xv = ((const float4*)x)[i];
        float4 rv = ((float4*)outq)[i];
        float4 qv;
        qv.x = xv.x - rv.x;
        qv.y = xv.y - rv.y;
        qv.z = xv.z - rv.z;
        qv.w = xv.w - rv.w;
        ((float4*)outq)[i] = qv;
    }
}

extern "C" void kernel_launch(void* const* d_in, const int* in_sizes, int n_in,
                              void* d_out, int out_size, void* d_ws, size_t ws_size,
                              hipStream_t stream)
{
    const float* x   = (const float*)d_in[0];
    const float* cbs = (const float*)d_in[1];
    const int PD = in_sizes[0];                // 16777216
    const int P  = PD / D;                     // 32768
    const int nq = in_sizes[1] / (C * D);      // 8
    const int nblk = P / BMF;                  // 512

    float* out     = (float*)d_out;
    float* resid   = out;
    float* idx_out = out + (size_t)PD;
    float* losses  = idx_out + (size_t)P * nq;

    // ws: [0, 8M) cb f16 planes | +32KB cbn | + blockloss
    char* wsb = (char*)d_ws;
    uint4* cb_hi     = (uint4*)wsb;
    float* cbn       = (float*)(wsb + 8388608);
    float* blockloss = (float*)(wsb + 8421376);

    cbnorm_kernel<<<nq * C / 4, 256, 0, stream>>>(cbs, cbn);
    cb_split_kernel<<<nq * C * D / 8 / 256, 256, 0, stream>>>(cbs, cb_hi);

    for (int q = 0; q < nq; ++q) {
        const float* rin = (q == 0) ? x : resid;
        vq_fused_step<<<nblk, 512, 0, stream>>>(
            rin, resid,
            cb_hi + (size_t)q * 65536,
            cbs + (size_t)q * C * D,
            cbn + (size_t)q * C,
            idx_out, blockloss + (size_t)q * nblk, q, nq);
    }
    finalize_kernel<<<2048, 256, 0, stream>>>(x, out, blockloss, losses,
                                              1.f / (float)PD, PD / 4, nq, nblk);
}